// Round 1
// 140.282 us; speedup vs baseline: 1.0528x; 1.0528x over previous
//
#include <hip/hip_runtime.h>
#include <hip/hip_bf16.h>

// CausalMixer: B=128, T=64, NA=10, NV=16, K=4, SD=512, H=256, E=32. 8192 rows.
// Round 14: same 32-row/256-block tiling (B-operand L2 traffic unchanged) but
// 1024 threads = 16 waves/block -> 4 waves/SIMD (was 2). Per-wave strips
// 7->4 (phase A) and 5->3 (phase B); fake slots zero-filled, never loaded.
// Goal: hide ~200cy L2 latency in the fetch-bound phases.

typedef __hip_bfloat16 bf16;
typedef unsigned short ushort_t;
typedef __attribute__((ext_vector_type(8))) short short8;
typedef __attribute__((ext_vector_type(4))) float f32x4;

#define PA_OFF 0
#define PA_TILES 56                                  // N=896 padded (844 real)
#define PB_OFF (PA_TILES * 16 * 64 * 8 * 2)          // 917504
#define PB_TILES 38                                  // 0..33 w1l2, 34..35 w2l2, 36/37 w00l2
#define FB_OFF (PB_OFF + PB_TILES * 8 * 64 * 8 * 2)  // 1228800
#define NCST 2854
#define WS_NEED (size_t)(FB_OFF + NCST * 4 + 32)

#define MFMA16(a, b, c) __builtin_amdgcn_mfma_f32_16x16x32_bf16(a, b, c, 0, 0, 0)

__device__ __forceinline__ float us2f(ushort_t x) {
  unsigned u = ((unsigned)x) << 16; float f; __builtin_memcpy(&f, &u, 4); return f;
}
__device__ __forceinline__ ushort_t f2us(float v) {
  bf16 h = __float2bfloat16(v); ushort_t r; __builtin_memcpy(&r, &h, 2); return r;
}
template <bool F32>
__device__ __forceinline__ float LD(const void* p, size_t i) {
  if (F32) return ((const float*)p)[i];
  return us2f(((const ushort_t*)p)[i]);
}

// wave-level dtype probe: 1 = float32, 0 = bf16
__device__ __forceinline__ int detect_f32(const void* states) {
  const unsigned short* u = (const unsigned short*)states;
  int lane = threadIdx.x & 63;
  int bad = 0;
  for (int i = lane; i < 512; i += 64) {
    unsigned short x = u[i];
    int e = (x >> 7) & 0xFF;
    if (e > 140 || (((x & 0x7FFFu) != 0) && e < 100)) bad++;
  }
  for (int off = 32; off; off >>= 1) bad += __shfl_down(bad, off);
  return __shfl(bad, 0) > 20;
}

// packed-layout stores: element (n', k) -> MFMA lane order
__device__ __forceinline__ void pa_store(ushort_t* pa, int np, int k, ushort_t v) {
  int t = np >> 4, lm = np & 15, ks = k >> 5, qq = (k >> 3) & 3, j = k & 7;
  pa[(size_t)t * 8192 + ks * 512 + (qq * 16 + lm) * 8 + j] = v;
}
__device__ __forceinline__ void pb_store(ushort_t* pb, int np, int k, ushort_t v) {
  int t = np >> 4, lm = np & 15, ks = k >> 5, qq = (k >> 3) & 3, j = k & 7;
  pb[(size_t)t * 4096 + ks * 512 + (qq * 16 + lm) * 8 + j] = v;
}

// ---------------- prep ----------------
template <bool F32>
__device__ void prep_body(int gtid, int T, char* ws,
    const void* w00l1W, const void* w00l1b, const void* w00l2W, const void* w00l2b,
    const void* b00W, const void* b00b,
    const void* w01W, const void* w01b, const void* b01W, const void* b01b,
    const void* w1l1W, const void* w1l1b, const void* w1l2W, const void* w1l2b,
    const void* b1W, const void* b1b,
    const void* w2l1W, const void* w2l1b, const void* w2l2W, const void* w2l2b,
    const void* b2l1W, const void* b2l1b, const void* b2l2W, const void* b2l2b) {
  ushort_t* pa = (ushort_t*)(ws + PA_OFF);
  ushort_t* pb = (ushort_t*)(ws + PB_OFF);
  float* cst = (float*)(ws + FB_OFF);
  for (int i = gtid; i < 131072; i += T) {
    int k = i >> 8, n = i & 255;
    pa_store(pa, n, k, f2us(LD<F32>(w1l1W, i)));
    pa_store(pa, 256 + n, k, f2us(LD<F32>(w2l1W, i)));
    pa_store(pa, 512 + n, k, f2us(LD<F32>(w00l1W, i)));
  }
  for (int i = gtid; i < 16384; i += T) {
    int k = i >> 5, n = i & 31;
    pa_store(pa, 768 + n, k, f2us(LD<F32>(b1W, i)));
    pa_store(pa, 800 + n, k, f2us(LD<F32>(b2l1W, i)));
  }
  for (int i = gtid; i < 5120; i += T) {
    int k = i / 10, n = i % 10;
    pa_store(pa, 832 + n, k, f2us(LD<F32>(w01W, i)));
  }
  for (int i = gtid; i < 512; i += T) {
    pa_store(pa, 842, i, f2us(LD<F32>(b00W, i)));
    pa_store(pa, 843, i, f2us(LD<F32>(b01W, i)));
  }
  for (int z = gtid; z < 2048; z += T) {
    int ks = z >> 7, qq = (z >> 5) & 3, lm = 12 + ((z >> 3) & 3), j = z & 7;
    pa[(size_t)52 * 8192 + ks * 512 + (qq * 16 + lm) * 8 + j] = 0;
  }
  for (int i = gtid; i < 139264; i += T) {
    int k = i / 544, n = i % 544;
    pb_store(pb, n, k, f2us(LD<F32>(w1l2W, i)));
  }
  for (int i = gtid; i < 8192; i += T) {
    int k = i >> 5, n = i & 31;
    pb_store(pb, 544 + n, k, f2us(LD<F32>(w2l2W, i)));
  }
  // PB tiles 36/37: w00l2 (256x4) in cols 0..3, zeros elsewhere
  for (int i = gtid; i < 8192; i += T) {
    int k = i & 255, lm = (i >> 8) & 15, tt = 36 + (i >> 12);
    ushort_t v = (lm < 4) ? f2us(LD<F32>(w00l2W, k * 4 + lm)) : (ushort_t)0;
    pb_store(pb, tt * 16 + lm, k, v);
  }
  // consts
  for (int i = gtid; i < NCST; i += T) {
    float x;
    if (i < 896) {
      int c = i;
      if (c < 256) x = LD<F32>(w1l1b, c);
      else if (c < 512) x = LD<F32>(w2l1b, c - 256);
      else if (c < 768) x = LD<F32>(w00l1b, c - 512);
      else if (c < 800) x = LD<F32>(b1b, c - 768);
      else if (c < 832) x = LD<F32>(b2l1b, c - 800);
      else if (c < 842) x = LD<F32>(w01b, c - 832);
      else if (c == 842) x = LD<F32>(b00b, 0);
      else if (c == 843) x = LD<F32>(b01b, 0);
      else x = 0.f;
    } else if (i < 1536) {
      int c = i - 896;
      x = (c < 544) ? LD<F32>(w1l2b, c) : (c < 576 ? LD<F32>(w2l2b, c - 544) : 0.f);
    } else if (i < 1792) {
      int j = i - 1536; float s = 0.f;
      for (int z = 0; z < 16; ++z) s += LD<F32>(w00l1W, (size_t)(512 + z) * 256 + j);
      x = s;
    } else if (i < 2816) x = LD<F32>(w00l2W, i - 1792);
    else if (i < 2820) x = LD<F32>(w00l2b, i - 2816);
    else if (i < 2852) x = LD<F32>(b2l2W, i - 2820);
    else if (i == 2852) x = LD<F32>(b2l2b, 0);
    else { float s = 0.f; for (int z = 0; z < 16; ++z) s += LD<F32>(b00W, 512 + z); x = s; }
    cst[i] = x;
  }
}

__global__ __launch_bounds__(256) void prep_kernel(char* ws, const void* states,
    const void* w00l1W, const void* w00l1b, const void* w00l2W, const void* w00l2b,
    const void* b00W, const void* b00b,
    const void* w01W, const void* w01b, const void* b01W, const void* b01b,
    const void* w1l1W, const void* w1l1b, const void* w1l2W, const void* w1l2b,
    const void* b1W, const void* b1b,
    const void* w2l1W, const void* w2l1b, const void* w2l2W, const void* w2l2b,
    const void* b2l1W, const void* b2l1b, const void* b2l2W, const void* b2l2b) {
  int gtid = blockIdx.x * 256 + threadIdx.x;
  int T = gridDim.x * 256;
  if (detect_f32(states))
    prep_body<true>(gtid, T, ws, w00l1W, w00l1b, w00l2W, w00l2b, b00W, b00b,
        w01W, w01b, b01W, b01b, w1l1W, w1l1b, w1l2W, w1l2b, b1W, b1b,
        w2l1W, w2l1b, w2l2W, w2l2b, b2l1W, b2l1b, b2l2W, b2l2b);
  else
    prep_body<false>(gtid, T, ws, w00l1W, w00l1b, w00l2W, w00l2b, b00W, b00b,
        w01W, w01b, b01W, b01b, w1l1W, w1l1b, w1l2W, w1l2b, b1W, b1b,
        w2l1W, w2l1b, w2l2W, w2l2b, b2l1W, b2l1b, b2l2W, b2l2b);
}

// ---------------- main MFMA kernel: 32 rows/block, 16 waves ----------------
struct SmemM {
  union {
    __align__(16) ushort_t sA[2][8192];   // states, lane order (phase A only)
    __align__(16) ushort_t w1a[32][544];  // |w1 raw| bf16 (phase B output)
  } u;
  __align__(16) ushort_t Am1[2][4096];    // relu(s@w1l1+b), lane order
  __align__(16) ushort_t Am2[2][4096];    // relu(s@w2l1+b), lane order
  __align__(16) ushort_t hbC[2][4096];    // relu(s@w00l1+b), lane order
  __align__(16) ushort_t hbS[2][4096];    // relu(s@w00l1+b+hd), lane order
  float hd[256];
  float b1v[32][32];
  float rbv[32][32];
  float w2v[32][32];
  float w01v[32][12];
  float qv[32][10];
  unsigned char cr[32][64];
  float w0c[32][4], w0s[32][4];
  float gq[32][18];
  float gbv[32], b01v[32];
  float hid[32][33];
};

template <bool F32>
__device__ void mixer_body(SmemM& sm, const char* ws, int n0,
    const void* qvals, const int* crel, const void* states, void* out) {
  const int tid = threadIdx.x;                // 0..1023
  const int lane = tid & 63, wv = tid >> 6;   // 16 waves
  const int q = lane >> 4, lm = lane & 15;
  const int b_blk = n0 >> 6;
  const ushort_t* pa = (const ushort_t*)(ws + PA_OFF);
  const ushort_t* pb = (const ushort_t*)(ws + PB_OFF);
  const float* cstg = (const float*)(ws + FB_OFF);
  const short8 z8 = {0, 0, 0, 0, 0, 0, 0, 0};

  int sidx[4]; bool sreal[4];
#pragma unroll
  for (int i = 0; i < 4; ++i) {
    int s = wv + 16 * i;
    sreal[i] = (s < 53);
    sidx[i] = sreal[i] ? s : 0;
  }
  const ushort_t* baseA = pa + lane * 8;

  // ---- stage: batched deep loads; issue depth-3 A-phase B-tile ring ----
  short8 bA[3][4];
  if (F32) {
    f32x4 va[4];
#pragma unroll
    for (int it = 0; it < 2; ++it) {
      int fi = tid + it * 1024;
      int ln = fi & 63, ks = (fi >> 6) & 15, G = fi >> 10;
      int row = G * 16 + (ln & 15), col = ks * 32 + (ln >> 4) * 8;
      const f32x4* p = (const f32x4*)((const float*)states + (size_t)(n0 + row) * 512 + col);
      va[2 * it] = p[0];
      va[2 * it + 1] = p[1];
    }
#pragma unroll
    for (int i = 0; i < 4; ++i) {
      if (sreal[i]) {
#pragma unroll
        for (int d = 0; d < 3; ++d)
          bA[d][i] = *(const short8*)(baseA + (size_t)sidx[i] * 8192 + d * 512);
      } else {
#pragma unroll
        for (int d = 0; d < 3; ++d) bA[d][i] = z8;
      }
    }
#pragma unroll
    for (int it = 0; it < 2; ++it) {
      int fi = tid + it * 1024;
      int ln = fi & 63, ks = (fi >> 6) & 15, G = fi >> 10;
      f32x4 v0 = va[2 * it], v1 = va[2 * it + 1];
      ushort_t v[8];
      v[0] = f2us(v0[0]); v[1] = f2us(v0[1]); v[2] = f2us(v0[2]); v[3] = f2us(v0[3]);
      v[4] = f2us(v1[0]); v[5] = f2us(v1[1]); v[6] = f2us(v1[2]); v[7] = f2us(v1[3]);
      *(short8*)&sm.u.sA[G][(size_t)(ks * 64 + ln) * 8] = *(short8*)v;
    }
  } else {
    short8 vb[2];
#pragma unroll
    for (int it = 0; it < 2; ++it) {
      int fi = tid + it * 1024;
      int ln = fi & 63, ks = (fi >> 6) & 15, G = fi >> 10;
      int row = G * 16 + (ln & 15), col = ks * 32 + (ln >> 4) * 8;
      vb[it] = *(const short8*)((const ushort_t*)states + (size_t)(n0 + row) * 512 + col);
    }
#pragma unroll
    for (int i = 0; i < 4; ++i) {
      if (sreal[i]) {
#pragma unroll
        for (int d = 0; d < 3; ++d)
          bA[d][i] = *(const short8*)(baseA + (size_t)sidx[i] * 8192 + d * 512);
      } else {
#pragma unroll
        for (int d = 0; d < 3; ++d) bA[d][i] = z8;
      }
    }
#pragma unroll
    for (int it = 0; it < 2; ++it) {
      int fi = tid + it * 1024;
      int ln = fi & 63, ks = (fi >> 6) & 15, G = fi >> 10;
      *(short8*)&sm.u.sA[G][(size_t)(ks * 64 + ln) * 8] = vb[it];
    }
  }
  for (int i = tid; i < 320; i += 1024) sm.qv[i / 10][i % 10] = LD<F32>(qvals, (size_t)(n0 + i / 10) * 10 + i % 10);
  for (int i = tid; i < 2048; i += 1024) sm.cr[i >> 6][i & 63] = (unsigned char)crel[(size_t)n0 * 64 + i];
  if (tid < 256) sm.hd[tid] = cstg[1536 + tid];
  __syncthreads();

  // ---- Phase A: ks-outer, 4 strips/wave, depth-3 prefetch ring ----
  {
    f32x4 accA[4][2];
#pragma unroll
    for (int i = 0; i < 4; ++i) { accA[i][0] = (f32x4){0,0,0,0}; accA[i][1] = (f32x4){0,0,0,0}; }
#pragma unroll
    for (int ks = 0; ks < 16; ++ks) {
      const int d = ks % 3;
      short8 a0 = *(const short8*)&sm.u.sA[0][(ks * 64 + lane) * 8];
      short8 a1 = *(const short8*)&sm.u.sA[1][(ks * 64 + lane) * 8];
#pragma unroll
      for (int i = 0; i < 4; ++i) {
        accA[i][0] = MFMA16(a0, bA[d][i], accA[i][0]);
        accA[i][1] = MFMA16(a1, bA[d][i], accA[i][1]);
      }
      if (ks + 3 < 16) {
#pragma unroll
        for (int i = 0; i < 4; ++i)
          if (sreal[i])
            bA[d][i] = *(const short8*)(baseA + (size_t)sidx[i] * 8192 + (ks + 3) * 512);
      }
    }
    // writeback
#pragma unroll
    for (int i = 0; i < 4; ++i) {
      if (!sreal[i]) continue;
      int c = sidx[i] * 16 + lm;
      if (c >= 844) continue;
      float bias = cstg[c];
      int ks2 = (c & 255) >> 5, q2 = (c >> 3) & 3, j2 = c & 7;
      int li = (ks2 * 64 + q2 * 16 + q * 4) * 8 + j2;
#pragma unroll
      for (int G = 0; G < 2; ++G) {
        f32x4 acc = accA[i][G];
        int rb = G * 16 + q * 4;
        if (c < 256) {
#pragma unroll
          for (int g = 0; g < 4; ++g) {
            float v = acc[g] + bias;
            sm.Am1[G][li + g * 8] = f2us(v > 0.f ? v : 0.f);
          }
        } else if (c < 512) {
#pragma unroll
          for (int g = 0; g < 4; ++g) {
            float v = acc[g] + bias;
            sm.Am2[G][li + g * 8] = f2us(v > 0.f ? v : 0.f);
          }
        } else if (c < 768) {
          float hdv = sm.hd[c - 512];
#pragma unroll
          for (int g = 0; g < 4; ++g) {
            float v = acc[g] + bias;
            sm.hbC[G][li + g * 8] = f2us(v > 0.f ? v : 0.f);
            float vs = v + hdv;
            sm.hbS[G][li + g * 8] = f2us(vs > 0.f ? vs : 0.f);
          }
        } else if (c < 800) {
#pragma unroll
          for (int g = 0; g < 4; ++g) sm.b1v[rb + g][c - 768] = acc[g] + bias;
        } else if (c < 832) {
#pragma unroll
          for (int g = 0; g < 4; ++g) { float v = acc[g] + bias; sm.rbv[rb + g][c - 800] = v > 0.f ? v : 0.f; }
        } else if (c < 842) {
#pragma unroll
          for (int g = 0; g < 4; ++g) sm.w01v[rb + g][c - 832] = acc[g] + bias;
        } else if (c == 842) {
#pragma unroll
          for (int g = 0; g < 4; ++g) sm.gbv[rb + g] = acc[g] + bias;
        } else {
#pragma unroll
          for (int g = 0; g < 4; ++g) sm.b01v[rb + g] = acc[g] + bias;
        }
      }
    }
  }

  // phase-B strips + depth-3 ring issued before the barrier
  int tix[3]; bool treal[3];
#pragma unroll
  for (int i = 0; i < 3; ++i) {
    int t = wv + 16 * i;
    treal[i] = (t < 38);
    tix[i] = treal[i] ? t : 0;
  }
  const ushort_t* baseB = pb + lane * 8;
  short8 bB[3][3];
#pragma unroll
  for (int i = 0; i < 3; ++i) {
    if (treal[i]) {
#pragma unroll
      for (int d = 0; d < 3; ++d)
        bB[d][i] = *(const short8*)(baseB + (size_t)tix[i] * 4096 + d * 512);
    } else {
#pragma unroll
      for (int d = 0; d < 3; ++d) bB[d][i] = z8;
    }
  }
  __syncthreads();

  // ---- Phase B: 38 tiles, depth-3 ring. A per strip: Am1 / Am2 / hbC / hbS ----
  {
    const ushort_t* As0[3]; const ushort_t* As1[3];
#pragma unroll
    for (int i = 0; i < 3; ++i) {
      int t = tix[i];
      As0[i] = (t < 34) ? sm.Am1[0] : (t < 36 ? sm.Am2[0] : (t == 36 ? sm.hbC[0] : sm.hbS[0]));
      As1[i] = (t < 34) ? sm.Am1[1] : (t < 36 ? sm.Am2[1] : (t == 36 ? sm.hbC[1] : sm.hbS[1]));
    }
    f32x4 accB[3][2];
#pragma unroll
    for (int i = 0; i < 3; ++i) { accB[i][0] = (f32x4){0,0,0,0}; accB[i][1] = (f32x4){0,0,0,0}; }
#pragma unroll
    for (int ks = 0; ks < 8; ++ks) {
      const int d = ks % 3;
      int ao = (ks * 64 + lane) * 8;
#pragma unroll
      for (int i = 0; i < 3; ++i) {
        short8 x0 = *(const short8*)(As0[i] + ao);
        short8 x1 = *(const short8*)(As1[i] + ao);
        accB[i][0] = MFMA16(x0, bB[d][i], accB[i][0]);
        accB[i][1] = MFMA16(x1, bB[d][i], accB[i][1]);
      }
      if (ks + 3 < 8) {
#pragma unroll
        for (int i = 0; i < 3; ++i)
          if (treal[i])
            bB[d][i] = *(const short8*)(baseB + (size_t)tix[i] * 4096 + (ks + 3) * 512);
      }
    }
#pragma unroll
    for (int i = 0; i < 3; ++i) {
      if (!treal[i]) continue;
      int t = tix[i];
      int c = t * 16 + lm;
#pragma unroll
      for (int G = 0; G < 2; ++G) {
        f32x4 acc = accB[i][G];
        int rb = G * 16 + q * 4;
        if (t < 34) {
          float bias = cstg[896 + c];
#pragma unroll
          for (int g = 0; g < 4; ++g) sm.u.w1a[rb + g][c] = f2us(fabsf(acc[g] + bias));
        } else if (t < 36) {
          float bias = cstg[896 + c];
          int e = c - 544;
#pragma unroll
          for (int g = 0; g < 4; ++g) sm.w2v[rb + g][e] = fabsf(acc[g] + bias);
        } else if (t == 36) {
          if (lm < 4) {
            float bias = cstg[2816 + lm];
#pragma unroll
            for (int g = 0; g < 4; ++g) sm.w0c[rb + g][lm] = acc[g] + bias;
          }
        } else {
          if (lm < 4) {
            float bias = cstg[2816 + lm];
#pragma unroll
            for (int g = 0; g < 4; ++g) sm.w0s[rb + g][lm] = acc[g] + bias;
          }
        }
      }
    }
  }
  __syncthreads();

  // ---- C2: gq ----
  if (tid < 512) {
    int r = tid >> 4, v = tid & 15;
    bool sp = (v == b_blk);
    const float* w0 = sp ? sm.w0s[r] : sm.w0c[r];
    float g = sm.gbv[r] + (sp ? cstg[2853] : 0.f);
#pragma unroll
    for (int k = 0; k < 4; ++k) {
      int a = sm.cr[r][k * 16 + v];
      g = fmaf(sm.qv[r][a], fabsf(w0[k]), g);
    }
    sm.gq[r][v] = g;
  }
  if (tid < 32) {
    float o = sm.b01v[tid];
#pragma unroll
    for (int a = 0; a < 10; ++a) o = fmaf(sm.qv[tid][a], sm.w01v[tid][a], o);
    sm.gq[tid][16] = o;
  }
  __syncthreads();

  // ---- C3: hidden = elu(sum_v gq*|w1| + b1); fuse *w2 + rb*b2l2W ----
  {
    int r = tid >> 5, e = tid & 31;
    float h = sm.b1v[r][e];
#pragma unroll
    for (int v = 0; v < 17; ++v) h = fmaf(sm.gq[r][v], us2f(sm.u.w1a[r][v * 32 + e]), h);
    float hid = h > 0.f ? h : (expf(h) - 1.f);
    sm.hid[r][e] = hid * sm.w2v[r][e] + sm.rbv[r][e] * cstg[2820 + e];
  }
  __syncthreads();

  // ---- C4: reduce + store ----
  if (tid < 32) {
    float y = cstg[2852];
#pragma unroll
    for (int e = 0; e < 32; ++e) y += sm.hid[tid][e];
    if (F32) ((float*)out)[n0 + tid] = y;
    else ((bf16*)out)[n0 + tid] = __float2bfloat16(y);
  }
}

__global__ __launch_bounds__(1024, 4) void causal_mixer_mfma(const char* ws,
    const void* qvals, const int* crel, const void* states, void* out) {
  __shared__ SmemM sm;
  int n0 = blockIdx.x * 32;
  if (detect_f32(states))
    mixer_body<true>(sm, ws, n0, qvals, crel, states, out);
  else
    mixer_body<false>(sm, ws, n0, qvals, crel, states, out);
}

extern "C" void kernel_launch(void* const* d_in, const int* in_sizes, int n_in,
                              void* d_out, int out_size, void* d_ws, size_t ws_size,
                              hipStream_t stream) {
  char* ws = (char*)d_ws;
  hipLaunchKernelGGL(prep_kernel, dim3(512), dim3(256), 0, stream, ws, d_in[2],
      d_in[3], d_in[4], d_in[5], d_in[6], d_in[7], d_in[8],
      d_in[9], d_in[10], d_in[11], d_in[12],
      d_in[13], d_in[14], d_in[15], d_in[16], d_in[17], d_in[18],
      d_in[19], d_in[20], d_in[21], d_in[22], d_in[23], d_in[24],
      d_in[25], d_in[26]);
  hipLaunchKernelGGL(causal_mixer_mfma, dim3(256), dim3(1024), 0, stream, ws,
      d_in[0], (const int*)d_in[1], d_in[2], d_out);
}

// Round 3
// 137.935 us; speedup vs baseline: 1.0708x; 1.0170x over previous
//
#include <hip/hip_runtime.h>
#include <hip/hip_bf16.h>

// CausalMixer: B=128, T=64, NA=10, NV=16, K=4, SD=512, H=256, E=32. 8192 rows.
// Round 16: R15 with the PA-tiles-48..51 loop bound fixed (8192 -> 4096).
// R15's bug: mat = u>>11 ran 0..3, writing b2l1W into tiles 52..55 and
// corrupting w01/b00/b01 (tile 52). 16B packed prep stores + fused C3/C4 kept.

typedef __hip_bfloat16 bf16;
typedef unsigned short ushort_t;
typedef __attribute__((ext_vector_type(8))) short short8;
typedef __attribute__((ext_vector_type(4))) float f32x4;

#define PA_OFF 0
#define PA_TILES 56                                  // N=896 padded (844 real)
#define PB_OFF (PA_TILES * 16 * 64 * 8 * 2)          // 917504
#define PB_TILES 38                                  // 0..33 w1l2, 34..35 w2l2, 36/37 w00l2
#define FB_OFF (PB_OFF + PB_TILES * 8 * 64 * 8 * 2)  // 1228800
#define NCST 2854
#define WS_NEED (size_t)(FB_OFF + NCST * 4 + 32)

#define MFMA16(a, b, c) __builtin_amdgcn_mfma_f32_16x16x32_bf16(a, b, c, 0, 0, 0)

__device__ __forceinline__ float us2f(ushort_t x) {
  unsigned u = ((unsigned)x) << 16; float f; __builtin_memcpy(&f, &u, 4); return f;
}
__device__ __forceinline__ ushort_t f2us(float v) {
  bf16 h = __float2bfloat16(v); ushort_t r; __builtin_memcpy(&r, &h, 2); return r;
}
template <bool F32>
__device__ __forceinline__ float LD(const void* p, size_t i) {
  if (F32) return ((const float*)p)[i];
  return us2f(((const ushort_t*)p)[i]);
}

// wave-level dtype probe: 1 = float32, 0 = bf16
__device__ __forceinline__ int detect_f32(const void* states) {
  const unsigned short* u = (const unsigned short*)states;
  int lane = threadIdx.x & 63;
  int bad = 0;
  for (int i = lane; i < 512; i += 64) {
    unsigned short x = u[i];
    int e = (x >> 7) & 0xFF;
    if (e > 140 || (((x & 0x7FFFu) != 0) && e < 100)) bad++;
  }
  for (int off = 32; off; off >>= 1) bad += __shfl_down(bad, off);
  return __shfl(bad, 0) > 20;
}

// packed-layout scalar stores: element (n', k) -> MFMA lane order
__device__ __forceinline__ void pa_store(ushort_t* pa, int np, int k, ushort_t v) {
  int t = np >> 4, lm = np & 15, ks = k >> 5, qq = (k >> 3) & 3, j = k & 7;
  pa[(size_t)t * 8192 + ks * 512 + (qq * 16 + lm) * 8 + j] = v;
}
__device__ __forceinline__ void pb_store(ushort_t* pb, int np, int k, ushort_t v) {
  int t = np >> 4, lm = np & 15, ks = k >> 5, qq = (k >> 3) & 3, j = k & 7;
  pb[(size_t)t * 4096 + ks * 512 + (qq * 16 + lm) * 8 + j] = v;
}

// ---------------- prep ----------------
template <bool F32>
__device__ void prep_body(int gtid, int T, char* ws,
    const void* w00l1W, const void* w00l1b, const void* w00l2W, const void* w00l2b,
    const void* b00W, const void* b00b,
    const void* w01W, const void* w01b, const void* b01W, const void* b01b,
    const void* w1l1W, const void* w1l1b, const void* w1l2W, const void* w1l2b,
    const void* b1W, const void* b1b,
    const void* w2l1W, const void* w2l1b, const void* w2l2W, const void* w2l2b,
    const void* b2l1W, const void* b2l1b, const void* b2l2W, const void* b2l2b) {
  ushort_t* pa = (ushort_t*)(ws + PA_OFF);
  ushort_t* pb = (ushort_t*)(ws + PB_OFF);
  float* cst = (float*)(ws + FB_OFF);

  // PA tiles 0..47: w1l1W / w2l1W / w00l1W (512x256, i = k*256+n), 16B stores
  for (int u = gtid; u < 49152; u += T) {
    int lm = u & 15, qq = (u >> 4) & 3, ks = (u >> 6) & 15, t16 = (u >> 10) & 15, mat = u >> 14;
    const void* src = (mat == 0) ? w1l1W : (mat == 1 ? w2l1W : w00l1W);
    int n = t16 * 16 + lm;
    int kbase = ks * 32 + qq * 8;
    ushort_t v[8];
#pragma unroll
    for (int j = 0; j < 8; ++j) v[j] = f2us(LD<F32>(src, (size_t)(kbase + j) * 256 + n));
    int t = mat * 16 + t16;
    *(short8*)(pa + (size_t)t * 8192 + ks * 512 + (qq * 16 + lm) * 8) = *(short8*)v;
  }
  // PA tiles 48..51: b1W / b2l1W (512x32, i = k*32+n), 16B stores
  // 4096 items: 16 lm x 4 qq x 16 ks x 2 t2 x 2 mat (each item = 8 elements)
  for (int u = gtid; u < 4096; u += T) {
    int lm = u & 15, qq = (u >> 4) & 3, ks = (u >> 6) & 15, t2 = (u >> 10) & 1, mat = u >> 11;
    const void* src = (mat == 0) ? b1W : b2l1W;
    int n = t2 * 16 + lm;
    int kbase = ks * 32 + qq * 8;
    ushort_t v[8];
#pragma unroll
    for (int j = 0; j < 8; ++j) v[j] = f2us(LD<F32>(src, (size_t)(kbase + j) * 32 + n));
    int t = 48 + mat * 2 + t2;
    *(short8*)(pa + (size_t)t * 8192 + ks * 512 + (qq * 16 + lm) * 8) = *(short8*)v;
  }
  // PA tile 52: w01W (512x10) cols 0..9, scalar
  for (int i = gtid; i < 5120; i += T) {
    int k = i / 10, n = i % 10;
    pa_store(pa, 832 + n, k, f2us(LD<F32>(w01W, i)));
  }
  for (int i = gtid; i < 512; i += T) {
    pa_store(pa, 842, i, f2us(LD<F32>(b00W, i)));
    pa_store(pa, 843, i, f2us(LD<F32>(b01W, i)));
  }
  for (int z = gtid; z < 2048; z += T) {
    int ks = z >> 7, qq = (z >> 5) & 3, lm = 12 + ((z >> 3) & 3), j = z & 7;
    pa[(size_t)52 * 8192 + ks * 512 + (qq * 16 + lm) * 8 + j] = 0;
  }
  // PB tiles 0..33: w1l2W (256x544, i = k*544+n), 16B stores
  for (int u = gtid; u < 17408; u += T) {
    int lm = u & 15, qq = (u >> 4) & 3, ks = (u >> 6) & 7, t = u >> 9;
    int n = t * 16 + lm;
    int kbase = ks * 32 + qq * 8;
    ushort_t v[8];
#pragma unroll
    for (int j = 0; j < 8; ++j) v[j] = f2us(LD<F32>(w1l2W, (size_t)(kbase + j) * 544 + n));
    *(short8*)(pb + (size_t)t * 4096 + ks * 512 + (qq * 16 + lm) * 8) = *(short8*)v;
  }
  // PB tiles 34..35: w2l2W (256x32, i = k*32+n), 16B stores
  for (int u = gtid; u < 1024; u += T) {
    int lm = u & 15, qq = (u >> 4) & 3, ks = (u >> 6) & 7, t2 = u >> 9;
    int n = t2 * 16 + lm;
    int kbase = ks * 32 + qq * 8;
    ushort_t v[8];
#pragma unroll
    for (int j = 0; j < 8; ++j) v[j] = f2us(LD<F32>(w2l2W, (size_t)(kbase + j) * 32 + n));
    *(short8*)(pb + (size_t)(34 + t2) * 4096 + ks * 512 + (qq * 16 + lm) * 8) = *(short8*)v;
  }
  // PB tiles 36/37: w00l2 (256x4) in cols 0..3, zeros elsewhere, 16B stores
  for (int u = gtid; u < 1024; u += T) {
    int lm = u & 15, qq = (u >> 4) & 3, ks = (u >> 6) & 7, tt = u >> 9;
    int kbase = ks * 32 + qq * 8;
    ushort_t v[8];
#pragma unroll
    for (int j = 0; j < 8; ++j)
      v[j] = (lm < 4) ? f2us(LD<F32>(w00l2W, (size_t)(kbase + j) * 4 + lm)) : (ushort_t)0;
    *(short8*)(pb + (size_t)(36 + tt) * 4096 + ks * 512 + (qq * 16 + lm) * 8) = *(short8*)v;
  }
  // consts
  for (int i = gtid; i < NCST; i += T) {
    float x;
    if (i < 896) {
      int c = i;
      if (c < 256) x = LD<F32>(w1l1b, c);
      else if (c < 512) x = LD<F32>(w2l1b, c - 256);
      else if (c < 768) x = LD<F32>(w00l1b, c - 512);
      else if (c < 800) x = LD<F32>(b1b, c - 768);
      else if (c < 832) x = LD<F32>(b2l1b, c - 800);
      else if (c < 842) x = LD<F32>(w01b, c - 832);
      else if (c == 842) x = LD<F32>(b00b, 0);
      else if (c == 843) x = LD<F32>(b01b, 0);
      else x = 0.f;
    } else if (i < 1536) {
      int c = i - 896;
      x = (c < 544) ? LD<F32>(w1l2b, c) : (c < 576 ? LD<F32>(w2l2b, c - 544) : 0.f);
    } else if (i < 1792) {
      int j = i - 1536; float s = 0.f;
      for (int z = 0; z < 16; ++z) s += LD<F32>(w00l1W, (size_t)(512 + z) * 256 + j);
      x = s;
    } else if (i < 2816) x = LD<F32>(w00l2W, i - 1792);
    else if (i < 2820) x = LD<F32>(w00l2b, i - 2816);
    else if (i < 2852) x = LD<F32>(b2l2W, i - 2820);
    else if (i == 2852) x = LD<F32>(b2l2b, 0);
    else { float s = 0.f; for (int z = 0; z < 16; ++z) s += LD<F32>(b00W, 512 + z); x = s; }
    cst[i] = x;
  }
}

__global__ __launch_bounds__(256) void prep_kernel(char* ws, const void* states,
    const void* w00l1W, const void* w00l1b, const void* w00l2W, const void* w00l2b,
    const void* b00W, const void* b00b,
    const void* w01W, const void* w01b, const void* b01W, const void* b01b,
    const void* w1l1W, const void* w1l1b, const void* w1l2W, const void* w1l2b,
    const void* b1W, const void* b1b,
    const void* w2l1W, const void* w2l1b, const void* w2l2W, const void* w2l2b,
    const void* b2l1W, const void* b2l1b, const void* b2l2W, const void* b2l2b) {
  int gtid = blockIdx.x * 256 + threadIdx.x;
  int T = gridDim.x * 256;
  if (detect_f32(states))
    prep_body<true>(gtid, T, ws, w00l1W, w00l1b, w00l2W, w00l2b, b00W, b00b,
        w01W, w01b, b01W, b01b, w1l1W, w1l1b, w1l2W, w1l2b, b1W, b1b,
        w2l1W, w2l1b, w2l2W, w2l2b, b2l1W, b2l1b, b2l2W, b2l2b);
  else
    prep_body<false>(gtid, T, ws, w00l1W, w00l1b, w00l2W, w00l2b, b00W, b00b,
        w01W, w01b, b01W, b01b, w1l1W, w1l1b, w1l2W, w1l2b, b1W, b1b,
        w2l1W, w2l1b, w2l2W, w2l2b, b2l1W, b2l1b, b2l2W, b2l2b);
}

// ---------------- main MFMA kernel: 32 rows/block, 16 waves ----------------
struct SmemM {
  union {
    __align__(16) ushort_t sA[2][8192];   // states, lane order (phase A only)
    __align__(16) ushort_t w1a[32][544];  // |w1 raw| bf16 (phase B output)
  } u;
  __align__(16) ushort_t Am1[2][4096];    // relu(s@w1l1+b), lane order
  __align__(16) ushort_t Am2[2][4096];    // relu(s@w2l1+b), lane order
  __align__(16) ushort_t hbC[2][4096];    // relu(s@w00l1+b), lane order
  __align__(16) ushort_t hbS[2][4096];    // relu(s@w00l1+b+hd), lane order
  float hd[256];
  float b1v[32][32];
  float rbv[32][32];
  float w2v[32][32];
  float w01v[32][12];
  float qv[32][10];
  unsigned char cr[32][64];
  float w0c[32][4], w0s[32][4];
  float gq[32][18];
  float gbv[32], b01v[32];
};

template <bool F32>
__device__ void mixer_body(SmemM& sm, const char* ws, int n0,
    const void* qvals, const int* crel, const void* states, void* out) {
  const int tid = threadIdx.x;                // 0..1023
  const int lane = tid & 63, wv = tid >> 6;   // 16 waves
  const int q = lane >> 4, lm = lane & 15;
  const int b_blk = n0 >> 6;
  const ushort_t* pa = (const ushort_t*)(ws + PA_OFF);
  const ushort_t* pb = (const ushort_t*)(ws + PB_OFF);
  const float* cstg = (const float*)(ws + FB_OFF);
  const short8 z8 = {0, 0, 0, 0, 0, 0, 0, 0};

  int sidx[4]; bool sreal[4];
#pragma unroll
  for (int i = 0; i < 4; ++i) {
    int s = wv + 16 * i;
    sreal[i] = (s < 53);
    sidx[i] = sreal[i] ? s : 0;
  }
  const ushort_t* baseA = pa + lane * 8;

  // ---- stage: batched deep loads; issue depth-3 A-phase B-tile ring ----
  short8 bA[3][4];
  if (F32) {
    f32x4 va[4];
#pragma unroll
    for (int it = 0; it < 2; ++it) {
      int fi = tid + it * 1024;
      int ln = fi & 63, ks = (fi >> 6) & 15, G = fi >> 10;
      int row = G * 16 + (ln & 15), col = ks * 32 + (ln >> 4) * 8;
      const f32x4* p = (const f32x4*)((const float*)states + (size_t)(n0 + row) * 512 + col);
      va[2 * it] = p[0];
      va[2 * it + 1] = p[1];
    }
#pragma unroll
    for (int i = 0; i < 4; ++i) {
      if (sreal[i]) {
#pragma unroll
        for (int d = 0; d < 3; ++d)
          bA[d][i] = *(const short8*)(baseA + (size_t)sidx[i] * 8192 + d * 512);
      } else {
#pragma unroll
        for (int d = 0; d < 3; ++d) bA[d][i] = z8;
      }
    }
#pragma unroll
    for (int it = 0; it < 2; ++it) {
      int fi = tid + it * 1024;
      int ln = fi & 63, ks = (fi >> 6) & 15, G = fi >> 10;
      f32x4 v0 = va[2 * it], v1 = va[2 * it + 1];
      ushort_t v[8];
      v[0] = f2us(v0[0]); v[1] = f2us(v0[1]); v[2] = f2us(v0[2]); v[3] = f2us(v0[3]);
      v[4] = f2us(v1[0]); v[5] = f2us(v1[1]); v[6] = f2us(v1[2]); v[7] = f2us(v1[3]);
      *(short8*)&sm.u.sA[G][(size_t)(ks * 64 + ln) * 8] = *(short8*)v;
    }
  } else {
    short8 vb[2];
#pragma unroll
    for (int it = 0; it < 2; ++it) {
      int fi = tid + it * 1024;
      int ln = fi & 63, ks = (fi >> 6) & 15, G = fi >> 10;
      int row = G * 16 + (ln & 15), col = ks * 32 + (ln >> 4) * 8;
      vb[it] = *(const short8*)((const ushort_t*)states + (size_t)(n0 + row) * 512 + col);
    }
#pragma unroll
    for (int i = 0; i < 4; ++i) {
      if (sreal[i]) {
#pragma unroll
        for (int d = 0; d < 3; ++d)
          bA[d][i] = *(const short8*)(baseA + (size_t)sidx[i] * 8192 + d * 512);
      } else {
#pragma unroll
        for (int d = 0; d < 3; ++d) bA[d][i] = z8;
      }
    }
#pragma unroll
    for (int it = 0; it < 2; ++it) {
      int fi = tid + it * 1024;
      int ln = fi & 63, ks = (fi >> 6) & 15, G = fi >> 10;
      *(short8*)&sm.u.sA[G][(size_t)(ks * 64 + ln) * 8] = vb[it];
    }
  }
  for (int i = tid; i < 320; i += 1024) sm.qv[i / 10][i % 10] = LD<F32>(qvals, (size_t)(n0 + i / 10) * 10 + i % 10);
  for (int i = tid; i < 2048; i += 1024) sm.cr[i >> 6][i & 63] = (unsigned char)crel[(size_t)n0 * 64 + i];
  if (tid < 256) sm.hd[tid] = cstg[1536 + tid];
  __syncthreads();

  // ---- Phase A: ks-outer, 4 strips/wave, depth-3 prefetch ring ----
  {
    f32x4 accA[4][2];
#pragma unroll
    for (int i = 0; i < 4; ++i) { accA[i][0] = (f32x4){0,0,0,0}; accA[i][1] = (f32x4){0,0,0,0}; }
#pragma unroll
    for (int ks = 0; ks < 16; ++ks) {
      const int d = ks % 3;
      short8 a0 = *(const short8*)&sm.u.sA[0][(ks * 64 + lane) * 8];
      short8 a1 = *(const short8*)&sm.u.sA[1][(ks * 64 + lane) * 8];
#pragma unroll
      for (int i = 0; i < 4; ++i) {
        accA[i][0] = MFMA16(a0, bA[d][i], accA[i][0]);
        accA[i][1] = MFMA16(a1, bA[d][i], accA[i][1]);
      }
      if (ks + 3 < 16) {
#pragma unroll
        for (int i = 0; i < 4; ++i)
          if (sreal[i])
            bA[d][i] = *(const short8*)(baseA + (size_t)sidx[i] * 8192 + (ks + 3) * 512);
      }
    }
    // writeback
#pragma unroll
    for (int i = 0; i < 4; ++i) {
      if (!sreal[i]) continue;
      int c = sidx[i] * 16 + lm;
      if (c >= 844) continue;
      float bias = cstg[c];
      int ks2 = (c & 255) >> 5, q2 = (c >> 3) & 3, j2 = c & 7;
      int li = (ks2 * 64 + q2 * 16 + q * 4) * 8 + j2;
#pragma unroll
      for (int G = 0; G < 2; ++G) {
        f32x4 acc = accA[i][G];
        int rb = G * 16 + q * 4;
        if (c < 256) {
#pragma unroll
          for (int g = 0; g < 4; ++g) {
            float v = acc[g] + bias;
            sm.Am1[G][li + g * 8] = f2us(v > 0.f ? v : 0.f);
          }
        } else if (c < 512) {
#pragma unroll
          for (int g = 0; g < 4; ++g) {
            float v = acc[g] + bias;
            sm.Am2[G][li + g * 8] = f2us(v > 0.f ? v : 0.f);
          }
        } else if (c < 768) {
          float hdv = sm.hd[c - 512];
#pragma unroll
          for (int g = 0; g < 4; ++g) {
            float v = acc[g] + bias;
            sm.hbC[G][li + g * 8] = f2us(v > 0.f ? v : 0.f);
            float vs = v + hdv;
            sm.hbS[G][li + g * 8] = f2us(vs > 0.f ? vs : 0.f);
          }
        } else if (c < 800) {
#pragma unroll
          for (int g = 0; g < 4; ++g) sm.b1v[rb + g][c - 768] = acc[g] + bias;
        } else if (c < 832) {
#pragma unroll
          for (int g = 0; g < 4; ++g) { float v = acc[g] + bias; sm.rbv[rb + g][c - 800] = v > 0.f ? v : 0.f; }
        } else if (c < 842) {
#pragma unroll
          for (int g = 0; g < 4; ++g) sm.w01v[rb + g][c - 832] = acc[g] + bias;
        } else if (c == 842) {
#pragma unroll
          for (int g = 0; g < 4; ++g) sm.gbv[rb + g] = acc[g] + bias;
        } else {
#pragma unroll
          for (int g = 0; g < 4; ++g) sm.b01v[rb + g] = acc[g] + bias;
        }
      }
    }
  }

  // phase-B strips + depth-3 ring issued before the barrier
  int tix[3]; bool treal[3];
#pragma unroll
  for (int i = 0; i < 3; ++i) {
    int t = wv + 16 * i;
    treal[i] = (t < 38);
    tix[i] = treal[i] ? t : 0;
  }
  const ushort_t* baseB = pb + lane * 8;
  short8 bB[3][3];
#pragma unroll
  for (int i = 0; i < 3; ++i) {
    if (treal[i]) {
#pragma unroll
      for (int d = 0; d < 3; ++d)
        bB[d][i] = *(const short8*)(baseB + (size_t)tix[i] * 4096 + d * 512);
    } else {
#pragma unroll
      for (int d = 0; d < 3; ++d) bB[d][i] = z8;
    }
  }
  __syncthreads();

  // ---- Phase B: 38 tiles, depth-3 ring. A per strip: Am1 / Am2 / hbC / hbS ----
  {
    const ushort_t* As0[3]; const ushort_t* As1[3];
#pragma unroll
    for (int i = 0; i < 3; ++i) {
      int t = tix[i];
      As0[i] = (t < 34) ? sm.Am1[0] : (t < 36 ? sm.Am2[0] : (t == 36 ? sm.hbC[0] : sm.hbS[0]));
      As1[i] = (t < 34) ? sm.Am1[1] : (t < 36 ? sm.Am2[1] : (t == 36 ? sm.hbC[1] : sm.hbS[1]));
    }
    f32x4 accB[3][2];
#pragma unroll
    for (int i = 0; i < 3; ++i) { accB[i][0] = (f32x4){0,0,0,0}; accB[i][1] = (f32x4){0,0,0,0}; }
#pragma unroll
    for (int ks = 0; ks < 8; ++ks) {
      const int d = ks % 3;
      int ao = (ks * 64 + lane) * 8;
#pragma unroll
      for (int i = 0; i < 3; ++i) {
        short8 x0 = *(const short8*)(As0[i] + ao);
        short8 x1 = *(const short8*)(As1[i] + ao);
        accB[i][0] = MFMA16(x0, bB[d][i], accB[i][0]);
        accB[i][1] = MFMA16(x1, bB[d][i], accB[i][1]);
      }
      if (ks + 3 < 8) {
#pragma unroll
        for (int i = 0; i < 3; ++i)
          if (treal[i])
            bB[d][i] = *(const short8*)(baseB + (size_t)tix[i] * 4096 + (ks + 3) * 512);
      }
    }
#pragma unroll
    for (int i = 0; i < 3; ++i) {
      if (!treal[i]) continue;
      int t = tix[i];
      int c = t * 16 + lm;
#pragma unroll
      for (int G = 0; G < 2; ++G) {
        f32x4 acc = accB[i][G];
        int rb = G * 16 + q * 4;
        if (t < 34) {
          float bias = cstg[896 + c];
#pragma unroll
          for (int g = 0; g < 4; ++g) sm.u.w1a[rb + g][c] = f2us(fabsf(acc[g] + bias));
        } else if (t < 36) {
          float bias = cstg[896 + c];
          int e = c - 544;
#pragma unroll
          for (int g = 0; g < 4; ++g) sm.w2v[rb + g][e] = fabsf(acc[g] + bias);
        } else if (t == 36) {
          if (lm < 4) {
            float bias = cstg[2816 + lm];
#pragma unroll
            for (int g = 0; g < 4; ++g) sm.w0c[rb + g][lm] = acc[g] + bias;
          }
        } else {
          if (lm < 4) {
            float bias = cstg[2816 + lm];
#pragma unroll
            for (int g = 0; g < 4; ++g) sm.w0s[rb + g][lm] = acc[g] + bias;
          }
        }
      }
    }
  }
  __syncthreads();

  // ---- C2: gq ----
  if (tid < 512) {
    int r = tid >> 4, v = tid & 15;
    bool sp = (v == b_blk);
    const float* w0 = sp ? sm.w0s[r] : sm.w0c[r];
    float g = sm.gbv[r] + (sp ? cstg[2853] : 0.f);
#pragma unroll
    for (int k = 0; k < 4; ++k) {
      int a = sm.cr[r][k * 16 + v];
      g = fmaf(sm.qv[r][a], fabsf(w0[k]), g);
    }
    sm.gq[r][v] = g;
  }
  if (tid < 32) {
    float o = sm.b01v[tid];
#pragma unroll
    for (int a = 0; a < 10; ++a) o = fmaf(sm.qv[tid][a], sm.w01v[tid][a], o);
    sm.gq[tid][16] = o;
  }
  __syncthreads();

  // ---- C3+C4 fused: hidden = elu(sum_v gq*|w1| + b1); *w2 + rb*b2l2W; row reduce ----
  {
    int r = tid >> 5, e = tid & 31;
    float h = sm.b1v[r][e];
#pragma unroll
    for (int v = 0; v < 17; ++v) h = fmaf(sm.gq[r][v], us2f(sm.u.w1a[r][v * 32 + e]), h);
    float hid = h > 0.f ? h : (expf(h) - 1.f);
    float val = hid * sm.w2v[r][e] + sm.rbv[r][e] * cstg[2820 + e];
#pragma unroll
    for (int m = 16; m; m >>= 1) val += __shfl_xor(val, m, 64);
    if (e == 0) {
      float y = val + cstg[2852];
      if (F32) ((float*)out)[n0 + r] = y;
      else ((bf16*)out)[n0 + r] = __float2bfloat16(y);
    }
  }
}

__global__ __launch_bounds__(1024, 4) void causal_mixer_mfma(const char* ws,
    const void* qvals, const int* crel, const void* states, void* out) {
  __shared__ SmemM sm;
  int n0 = blockIdx.x * 32;
  if (detect_f32(states))
    mixer_body<true>(sm, ws, n0, qvals, crel, states, out);
  else
    mixer_body<false>(sm, ws, n0, qvals, crel, states, out);
}

extern "C" void kernel_launch(void* const* d_in, const int* in_sizes, int n_in,
                              void* d_out, int out_size, void* d_ws, size_t ws_size,
                              hipStream_t stream) {
  char* ws = (char*)d_ws;
  hipLaunchKernelGGL(prep_kernel, dim3(512), dim3(256), 0, stream, ws, d_in[2],
      d_in[3], d_in[4], d_in[5], d_in[6], d_in[7], d_in[8],
      d_in[9], d_in[10], d_in[11], d_in[12],
      d_in[13], d_in[14], d_in[15], d_in[16], d_in[17], d_in[18],
      d_in[19], d_in[20], d_in[21], d_in[22], d_in[23], d_in[24],
      d_in[25], d_in[26]);
  hipLaunchKernelGGL(causal_mixer_mfma, dim3(256), dim3(1024), 0, stream, ws,
      d_in[0], (const int*)d_in[1], d_in[2], d_out);
}